// Round 7
// baseline (1536.918 us; speedup 1.0000x reference)
//
#include <hip/hip_runtime.h>

#define H4 128     // hidden
#define EE 768     // embedding
#define NL 20      // layers
#define TT 512     // seq len
#define G4 512     // 4*H
#define NBG 4      // batch groups of 16
#define CK 8       // timesteps per chunk
#define NCH (TT/CK)
#define RC 4       // ring slots (chunks) per flow
#define SLOT 4096  // ring bytes per step (64 lanes x 64B fragment image)
#define CHUNK (CK*SLOT)
#define FLOWB (RC*CHUNK)

typedef _Float16 v8h __attribute__((ext_vector_type(8)));
typedef _Float16 v4h __attribute__((ext_vector_type(4)));
typedef float v4f __attribute__((ext_vector_type(4)));
typedef unsigned int v4u __attribute__((ext_vector_type(4)));
typedef unsigned int v2u __attribute__((ext_vector_type(2)));

#if defined(__has_builtin)
#if __has_builtin(__builtin_amdgcn_exp2f) && __has_builtin(__builtin_amdgcn_rcpf)
#define EXP2F __builtin_amdgcn_exp2f
#define RCPF  __builtin_amdgcn_rcpf
#endif
#endif
#ifndef EXP2F
#define EXP2F exp2f
#define RCPF(x) (1.0f/(x))
#endif

__device__ __forceinline__ float fast_sig(float x) {
  float e = EXP2F(-1.44269504f * x);
  return RCPF(1.0f + e);
}
__device__ __forceinline__ float fast_tanh(float x) {
  float e = EXP2F(2.88539008f * x);   // e^(2x)
  return 1.0f - 2.0f * RCPF(1.0f + e);
}

// XOR swizzle within a [16 rows][256B] tile (full row-index spread).
__device__ __forceinline__ int swz(int row, int byteInRow) {
  return (row * 256 + byteInRow) ^ ((row & 15) << 4);
}

// ---------------- prep: fp16 weights, combined bias, zero flags ----------------
__global__ __launch_bounds__(256) void prep_kernel(
    const float* __restrict__ Wih0, const float* __restrict__ Whh0,
    const float* __restrict__ bih,  const float* __restrict__ bhh,
    const float* __restrict__ Wih,  const float* __restrict__ Whh,
    _Float16* __restrict__ W0h, _Float16* __restrict__ Wc,
    float* __restrict__ biasc, unsigned* __restrict__ flags)
{
  long idx = (long)blockIdx.x * 256 + threadIdx.x;
  const long NWC = (long)NL * G4 * 256;   // 2,621,440
  const long NW0 = (long)G4 * EE;         // 393,216
  const long NBI = (long)NL * G4;         // 10,240
  if (idx < NWC) {
    int l = (int)(idx >> 17);
    int rem = (int)(idx & 131071);
    int n = rem >> 8, kk = rem & 255;
    float v;
    if (l == 0) v = (kk < 128) ? 0.0f : Whh0[n * H4 + kk - 128];
    else v = (kk < 128) ? Wih[((long)(l-1) * G4 + n) * H4 + kk]
                        : Whh[((long)(l-1) * G4 + n) * H4 + kk - 128];
    Wc[idx] = (_Float16)v;
  } else if ((idx -= NWC) < NW0) {
    W0h[idx] = (_Float16)Wih0[idx];
  } else if ((idx -= NW0) < NBI) {
    int l = (int)(idx >> 9), n = (int)(idx & 511);
    biasc[idx] = (l == 0) ? 0.0f : (bih[(l-1) * G4 + n] + bhh[(l-1) * G4 + n]);
  } else if ((idx -= NBI) < 256) {
    flags[idx] = 0u;
  }
}

// ---------------- layer-0 input projection GEMM ----------------
// pre0 layout: [t][bg(4)][n2 = j*4+q (512)][b(16)] fp16 -> 16KB per (t,bg);
// a lane's 4 per-gate dwordx2 loads sit at offsets q*32 from one base.
__global__ __launch_bounds__(512) void pre0_gemm(
    const float* __restrict__ x, const _Float16* __restrict__ W0h,
    const float* __restrict__ bih0, const float* __restrict__ bhh0,
    _Float16* __restrict__ pre0)
{
  __shared__ __align__(16) unsigned char smem[46080];
  _Float16* sA = (_Float16*)smem;             // [64][40]
  _Float16* sB = (_Float16*)(smem + 5120);    // [512][40]
  _Float16* sC = (_Float16*)smem;             // alias: [256][72] bounce
  int t = blockIdx.x;
  int tid = threadIdx.x;
  int w = tid >> 6, lane = tid & 63;
  int l15 = lane & 15, kb = lane >> 4;

  v4f acc[4][4];
#pragma unroll
  for (int mi = 0; mi < 4; ++mi)
#pragma unroll
    for (int ni = 0; ni < 4; ++ni) acc[mi][ni] = (v4f){0.f, 0.f, 0.f, 0.f};

  int bA = tid >> 3, kqA = tid & 7;
  const float* xp = x + ((long)bA * TT + t) * EE + kqA * 4;
  const _Float16* wp = W0h + (long)tid * EE;

  for (int k0 = 0; k0 < EE; k0 += 32) {
    float4 xv = *(const float4*)(xp + k0);
    v4h xh = { (_Float16)xv.x, (_Float16)xv.y, (_Float16)xv.z, (_Float16)xv.w };
    *(v4h*)&sA[bA * 40 + kqA * 4] = xh;
#pragma unroll
    for (int c = 0; c < 4; ++c)
      *(v8h*)&sB[tid * 40 + c * 8] = *(const v8h*)(wp + k0 + c * 8);
    __syncthreads();
#pragma unroll
    for (int mi = 0; mi < 4; ++mi) {
      v8h a = *(const v8h*)&sA[(16 * mi + l15) * 40 + kb * 8];
#pragma unroll
      for (int ni = 0; ni < 4; ++ni) {
        v8h b = *(const v8h*)&sB[(64 * w + 16 * ni + l15) * 40 + kb * 8];
        acc[mi][ni] = __builtin_amdgcn_mfma_f32_16x16x32_f16(a, b, acc[mi][ni], 0, 0, 0);
      }
    }
    __syncthreads();
  }

#pragma unroll
  for (int hh2 = 0; hh2 < 2; ++hh2) {
    __syncthreads();
    if ((w >> 2) == hh2) {
      int wl = w & 3;
#pragma unroll
      for (int ni = 0; ni < 4; ++ni) {
        int nloc = 64 * wl + 16 * ni + l15;
        int n = 256 * hh2 + nloc;
        float bia = bih0[n] + bhh0[n];
#pragma unroll
        for (int mi = 0; mi < 4; ++mi)
#pragma unroll
          for (int r = 0; r < 4; ++r)
            sC[nloc * 72 + 16 * mi + 4 * kb + r] = (_Float16)(acc[mi][ni][r] + bia);
      }
    }
    __syncthreads();
    int row = tid >> 1, part = tid & 1;    // row: n-local 0..255, part: batch half
    int n = 256 * hh2 + row;
    int n2 = (n & 127) * 4 + (n >> 7);     // j*4 + q
#pragma unroll
    for (int g = 0; g < 2; ++g) {
      int bg = part * 2 + g;               // batch group of 16
      _Float16* po = pre0 + (((long)t * NBG + bg) * 512 + n2) * 16;
      *(v8h*)po       = *(const v8h*)&sC[row * 72 + bg * 16];
      *(v8h*)(po + 8) = *(const v8h*)&sC[row * 72 + bg * 16 + 8];
    }
  }
}

// ---------------- persistent pipelined LSTM ----------------
// 80 blocks (layer l, batch-group bg of 16). 8 waves; wave w owns j-strip
// [16w,16w+16) x 4 gates; weights register-resident; all M rows valid -> no
// lane repack. y/pre operands come straight from LLC ring / pre0 into
// registers (1-step prefetch, counted vmcnt). LDS = h ping-pong 2x4KB only.
__global__ __launch_bounds__(512, 1) void lstm_pipe(
    const _Float16* __restrict__ pre0, const _Float16* __restrict__ Wc,
    const float* __restrict__ biasc, _Float16* __restrict__ yring,
    unsigned* __restrict__ flags, float* __restrict__ out)
{
  __shared__ __align__(16) unsigned char lds[8192];
  const int l = blockIdx.x >> 2, bg = blockIdx.x & 3;
  const int tid = threadIdx.x, w = tid >> 6, lane = tid & 63;
  const int l15 = lane & 15, kb = lane >> 4;
  const int jloc = 16 * w + l15;

  // weight fragments resident for the whole kernel
  v8h bw[4][8];
  const _Float16* wbase = Wc + (long)l * G4 * 256;
#pragma unroll
  for (int q = 0; q < 4; ++q)
#pragma unroll
    for (int ks = 0; ks < 8; ++ks)
      bw[q][ks] = *(const v8h*)(wbase + (long)(128 * q + jloc) * 256 + ks * 32 + kb * 8);

  float bias_q[4];
#pragma unroll
  for (int q = 0; q < 4; ++q)
    bias_q[q] = (l == 0) ? 0.0f : biasc[l * G4 + 128 * q + jloc];

  // zero h ping-pong (512 x 16B = 8KB)
  *(v4u*)(lds + tid * 16) = (v4u){0u, 0u, 0u, 0u};

  const int myf = l * NBG + bg;
  const unsigned* fin  = flags + ((l > 0) ? (myf - NBG) : myf);
  const unsigned* fout = flags + ((l < NL - 1) ? (myf + NBG) : myf);
  unsigned* fme = flags + myf;
  char* ywr = (char*)yring + (long)myf * FLOWB;
  const char* yrd = (char*)yring + (long)(myf - NBG) * FLOWB;
  const char* pbase = (const char*)pre0 + (long)bg * 16384 + jloc * 128 + kb * 8;

  // ring-copy thread mapping (producer side)
  const int cks = tid >> 7, lane6 = (tid & 127) >> 1, chalf = tid & 1;
  const int csrc = swz(lane6 & 15, cks * 64 + (lane6 >> 4) * 16 + chalf * 8);
  const int cdst = cks * 1024 + lane6 * 16 + chalf * 8;

  v4f cst = (v4f){0.f, 0.f, 0.f, 0.f};
  v4u ya[4], yb[4];   // y fragment ping-pong (l>0)
  v2u pa[4], pb[4];   // pre-gate ping-pong (l==0)

  __syncthreads();

#define ISSUE_Y(D, yslot_, ts_) do { \
    const char* a_ = (yslot_) + (long)(ts_) * SLOT + lane * 16; \
    asm volatile("global_load_dwordx4 %0, %4, off sc0 sc1\n\t" \
                 "global_load_dwordx4 %1, %4, off offset:1024 sc0 sc1\n\t" \
                 "global_load_dwordx4 %2, %4, off offset:2048 sc0 sc1\n\t" \
                 "global_load_dwordx4 %3, %4, off offset:3072 sc0 sc1" \
                 : "=v"(D[0]), "=v"(D[1]), "=v"(D[2]), "=v"(D[3]) : "v"(a_)); \
  } while (0)

#define ISSUE_P(D, t_) do { \
    const char* a_ = pbase + (long)(t_) * (NBG * 16384); \
    asm volatile("global_load_dwordx2 %0, %4, off\n\t" \
                 "global_load_dwordx2 %1, %4, off offset:32\n\t" \
                 "global_load_dwordx2 %2, %4, off offset:64\n\t" \
                 "global_load_dwordx2 %3, %4, off offset:96" \
                 : "=v"(D[0]), "=v"(D[1]), "=v"(D[2]), "=v"(D[3]) : "v"(a_)); \
  } while (0)

#define STEP(ts_, CY, NY, CP, NP) do { \
    const int t = c * CK + (ts_); \
    const int p = t & 1; \
    if ((ts_) == 0 || l == NL - 1) asm volatile("s_waitcnt vmcnt(0)" ::: "memory"); \
    else asm volatile("s_waitcnt vmcnt(1)" ::: "memory"); \
    __builtin_amdgcn_sched_barrier(0); \
    v4f acc[4]; \
    _Pragma("unroll") \
    for (int q = 0; q < 4; ++q) \
      acc[q] = (v4f){bias_q[q], bias_q[q], bias_q[q], bias_q[q]}; \
    const unsigned char* hb = lds + p * 4096; \
    v8h hfr[4]; \
    _Pragma("unroll") \
    for (int ks = 0; ks < 4; ++ks) \
      hfr[ks] = *(const v8h*)(hb + swz(l15, ks * 64 + kb * 16)); \
    if (l > 0) { \
      _Pragma("unroll") \
      for (int ks = 0; ks < 4; ++ks) { \
        union { v4u u; v8h h; } cv_; cv_.u = CY[ks]; \
        _Pragma("unroll") \
        for (int q = 0; q < 4; ++q) \
          acc[q] = __builtin_amdgcn_mfma_f32_16x16x32_f16(cv_.h, bw[q][ks], acc[q], 0, 0, 0); \
      } \
    } else { \
      _Pragma("unroll") \
      for (int q = 0; q < 4; ++q) { \
        union { v2u u; _Float16 h[4]; } pv_; pv_.u = CP[q]; \
        _Pragma("unroll") \
        for (int r = 0; r < 4; ++r) acc[q][r] += (float)pv_.h[r]; \
      } \
    } \
    if ((ts_) < CK - 1) { \
      if (l > 0) ISSUE_Y(NY, yslot, (ts_) + 1); \
      else ISSUE_P(NP, t + 1); \
    } \
    _Pragma("unroll") \
    for (int ks = 0; ks < 4; ++ks) { \
      _Pragma("unroll") \
      for (int q = 0; q < 4; ++q) \
        acc[q] = __builtin_amdgcn_mfma_f32_16x16x32_f16(hfr[ks], bw[q][ks + 4], acc[q], 0, 0, 0); \
    } \
    float hf[4]; \
    _Pragma("unroll") \
    for (int r = 0; r < 4; ++r) { \
      float i_ = fast_sig(acc[0][r]); \
      float f_ = fast_sig(acc[1][r]); \
      float g_ = fast_tanh(acc[2][r]); \
      float o_ = fast_sig(acc[3][r]); \
      float cn = f_ * cst[r] + i_ * g_; \
      cst[r] = cn; \
      hf[r] = o_ * fast_tanh(cn); \
    } \
    unsigned char* hn = lds + (p ^ 1) * 4096; \
    _Pragma("unroll") \
    for (int r = 0; r < 4; ++r) \
      *(_Float16*)(hn + swz(4 * kb + r, jloc * 2)) = (_Float16)hf[r]; \
    if (l == NL - 1 && t == TT - 1) { \
      _Pragma("unroll") \
      for (int r = 0; r < 4; ++r) \
        out[(bg * 16 + 4 * kb + r) * H4 + jloc] = hf[r]; \
    } \
    asm volatile("s_waitcnt lgkmcnt(0)" ::: "memory"); \
    __builtin_amdgcn_s_barrier(); \
    __builtin_amdgcn_sched_barrier(0); \
    if (l < NL - 1) { \
      v2u hv = *(const v2u*)(lds + (p ^ 1) * 4096 + csrc); \
      char* dst_ = ywslot + (long)(ts_) * SLOT + cdst; \
      asm volatile("global_store_dwordx2 %0, %1, off sc0 sc1" :: "v"(dst_), "v"(hv)); \
    } \
  } while (0)

  for (int c = 0; c < NCH; ++c) {
    const char* yslot = yrd + (long)(c & (RC - 1)) * CHUNK;
    char* ywslot = ywr + (long)(c & (RC - 1)) * CHUNK;
    // producer backpressure first (its vmcnt(0) poll must not drain prefetch)
    if (l < NL - 1 && c >= RC) {
      unsigned f;
      for (;;) {
        asm volatile("global_load_dword %0, %1, off sc0 sc1\n\ts_waitcnt vmcnt(0)"
                     : "=v"(f) : "v"(fout));
        if (f >= (unsigned)(c - RC + 1)) break;
        __builtin_amdgcn_s_sleep(2);
      }
    }
    if (l > 0) {
      unsigned f;
      for (;;) {
        asm volatile("global_load_dword %0, %1, off sc0 sc1\n\ts_waitcnt vmcnt(0)"
                     : "=v"(f) : "v"(fin));
        if (f > (unsigned)c) break;
        __builtin_amdgcn_s_sleep(2);
      }
      ISSUE_Y(ya, yslot, 0);
    } else {
      ISSUE_P(pa, c * CK);
    }

#pragma unroll
    for (int ts = 0; ts < CK; ts += 2) {
      STEP(ts,     ya, yb, pa, pb);
      STEP(ts + 1, yb, ya, pb, pa);
    }

    // publish chunk c (each wave drains its ring stores; barrier; one flag store)
    asm volatile("s_waitcnt vmcnt(0)" ::: "memory");
    __builtin_amdgcn_s_barrier();
    __builtin_amdgcn_sched_barrier(0);
    if (tid == 0) {
      unsigned v = (unsigned)(c + 1);
      asm volatile("global_store_dword %0, %1, off sc0 sc1" :: "v"(fme), "v"(v) : "memory");
    }
  }
#undef STEP
#undef ISSUE_Y
#undef ISSUE_P
}

extern "C" void kernel_launch(void* const* d_in, const int* in_sizes, int n_in,
                              void* d_out, int out_size, void* d_ws, size_t ws_size,
                              hipStream_t stream)
{
  const float* x    = (const float*)d_in[0];
  const float* Wih0 = (const float*)d_in[1];
  const float* Whh0 = (const float*)d_in[2];
  const float* bih0 = (const float*)d_in[3];
  const float* bhh0 = (const float*)d_in[4];
  const float* Wih  = (const float*)d_in[5];
  const float* Whh  = (const float*)d_in[6];
  const float* bih  = (const float*)d_in[7];
  const float* bhh  = (const float*)d_in[8];
  float* out = (float*)d_out;
  char* ws = (char*)d_ws;

  _Float16* pre0  = (_Float16*)(ws);              // 33,554,432 B
  _Float16* W0h   = (_Float16*)(ws + 33554432);   //    786,432 B
  _Float16* Wc    = (_Float16*)(ws + 34340864);   //  5,242,880 B
  float*    bc    = (float*)   (ws + 39583744);   //     40,960 B
  _Float16* yring = (_Float16*)(ws + 39624704);   // 10,485,760 B (80 flows x 128KB)
  unsigned* flags = (unsigned*)(ws + 50110464);   //      1,024 B

  prep_kernel<<<11817, 256, 0, stream>>>(Wih0, Whh0, bih, bhh, Wih, Whh, W0h, Wc, bc, flags);
  pre0_gemm<<<TT, 512, 0, stream>>>(x, W0h, bih0, bhh0, pre0);
  lstm_pipe<<<NL * NBG, 512, 0, stream>>>(pre0, Wc, bc, yring, flags, out);
}

// Round 8
// 1108.960 us; speedup vs baseline: 1.3859x; 1.3859x over previous
//
#include <hip/hip_runtime.h>

#define H4 128     // hidden
#define EE 768     // embedding
#define NL 20      // layers
#define TT 512     // seq len
#define G4 512     // 4*H
#define NBG 4      // batch groups of 16
#define CK 8       // timesteps per chunk
#define NCH (TT/CK)
#define RC 4       // ring slots (chunks) per flow
#define SLOT 4096  // ring bytes per step (fragment-ordered image)
#define CHUNK (CK*SLOT)
#define FLOWB (RC*CHUNK)

typedef _Float16 v8h __attribute__((ext_vector_type(8)));
typedef _Float16 v4h __attribute__((ext_vector_type(4)));
typedef float v4f __attribute__((ext_vector_type(4)));
typedef unsigned int v4u __attribute__((ext_vector_type(4)));
typedef unsigned int v2u __attribute__((ext_vector_type(2)));

#if defined(__has_builtin)
#if __has_builtin(__builtin_amdgcn_exp2f) && __has_builtin(__builtin_amdgcn_rcpf)
#define EXP2F __builtin_amdgcn_exp2f
#define RCPF  __builtin_amdgcn_rcpf
#endif
#endif
#ifndef EXP2F
#define EXP2F exp2f
#define RCPF(x) (1.0f/(x))
#endif

__device__ __forceinline__ float fast_sig(float x) {
  float e = EXP2F(-1.44269504f * x);
  return RCPF(1.0f + e);
}
__device__ __forceinline__ float fast_tanh(float x) {
  float e = EXP2F(2.88539008f * x);   // e^(2x)
  return 1.0f - 2.0f * RCPF(1.0f + e);
}

// XOR swizzle within a [16 rows][256B] tile (proven conflict-free in r7: PMC=0).
__device__ __forceinline__ int swz(int row, int byteInRow) {
  return (row * 256 + byteInRow) ^ ((row & 15) << 4);
}

// ---------------- prep: fp16 weights, combined bias, zero flags ----------------
__global__ __launch_bounds__(256) void prep_kernel(
    const float* __restrict__ Wih0, const float* __restrict__ Whh0,
    const float* __restrict__ bih,  const float* __restrict__ bhh,
    const float* __restrict__ Wih,  const float* __restrict__ Whh,
    _Float16* __restrict__ W0h, _Float16* __restrict__ Wc,
    float* __restrict__ biasc, unsigned* __restrict__ flags)
{
  long idx = (long)blockIdx.x * 256 + threadIdx.x;
  const long NWC = (long)NL * G4 * 256;   // 2,621,440
  const long NW0 = (long)G4 * EE;         // 393,216
  const long NBI = (long)NL * G4;         // 10,240
  if (idx < NWC) {
    int l = (int)(idx >> 17);
    int rem = (int)(idx & 131071);
    int n = rem >> 8, kk = rem & 255;
    float v;
    if (l == 0) v = (kk < 128) ? 0.0f : Whh0[n * H4 + kk - 128];
    else v = (kk < 128) ? Wih[((long)(l-1) * G4 + n) * H4 + kk]
                        : Whh[((long)(l-1) * G4 + n) * H4 + kk - 128];
    Wc[idx] = (_Float16)v;
  } else if ((idx -= NWC) < NW0) {
    W0h[idx] = (_Float16)Wih0[idx];
  } else if ((idx -= NW0) < NBI) {
    int l = (int)(idx >> 9), n = (int)(idx & 511);
    biasc[idx] = (l == 0) ? 0.0f : (bih[(l-1) * G4 + n] + bhh[(l-1) * G4 + n]);
  } else if ((idx -= NBI) < 256) {
    flags[idx] = 0u;
  }
}

// ---------------- layer-0 input projection GEMM ----------------
// pre0 layout: [t][bg(4)][n2 = j*4+q (512)][b(16)] fp16 -> 16KB per (t,bg).
__global__ __launch_bounds__(512) void pre0_gemm(
    const float* __restrict__ x, const _Float16* __restrict__ W0h,
    const float* __restrict__ bih0, const float* __restrict__ bhh0,
    _Float16* __restrict__ pre0)
{
  __shared__ __align__(16) unsigned char smem[46080];
  _Float16* sA = (_Float16*)smem;             // [64][40]
  _Float16* sB = (_Float16*)(smem + 5120);    // [512][40]
  _Float16* sC = (_Float16*)smem;             // alias: [256][72] bounce
  int t = blockIdx.x;
  int tid = threadIdx.x;
  int w = tid >> 6, lane = tid & 63;
  int l15 = lane & 15, kb = lane >> 4;

  v4f acc[4][4];
#pragma unroll
  for (int mi = 0; mi < 4; ++mi)
#pragma unroll
    for (int ni = 0; ni < 4; ++ni) acc[mi][ni] = (v4f){0.f, 0.f, 0.f, 0.f};

  int bA = tid >> 3, kqA = tid & 7;
  const float* xp = x + ((long)bA * TT + t) * EE + kqA * 4;
  const _Float16* wp = W0h + (long)tid * EE;

  for (int k0 = 0; k0 < EE; k0 += 32) {
    float4 xv = *(const float4*)(xp + k0);
    v4h xh = { (_Float16)xv.x, (_Float16)xv.y, (_Float16)xv.z, (_Float16)xv.w };
    *(v4h*)&sA[bA * 40 + kqA * 4] = xh;
#pragma unroll
    for (int c = 0; c < 4; ++c)
      *(v8h*)&sB[tid * 40 + c * 8] = *(const v8h*)(wp + k0 + c * 8);
    __syncthreads();
#pragma unroll
    for (int mi = 0; mi < 4; ++mi) {
      v8h a = *(const v8h*)&sA[(16 * mi + l15) * 40 + kb * 8];
#pragma unroll
      for (int ni = 0; ni < 4; ++ni) {
        v8h b = *(const v8h*)&sB[(64 * w + 16 * ni + l15) * 40 + kb * 8];
        acc[mi][ni] = __builtin_amdgcn_mfma_f32_16x16x32_f16(a, b, acc[mi][ni], 0, 0, 0);
      }
    }
    __syncthreads();
  }

#pragma unroll
  for (int hh2 = 0; hh2 < 2; ++hh2) {
    __syncthreads();
    if ((w >> 2) == hh2) {
      int wl = w & 3;
#pragma unroll
      for (int ni = 0; ni < 4; ++ni) {
        int nloc = 64 * wl + 16 * ni + l15;
        int n = 256 * hh2 + nloc;
        float bia = bih0[n] + bhh0[n];
#pragma unroll
        for (int mi = 0; mi < 4; ++mi)
#pragma unroll
          for (int r = 0; r < 4; ++r)
            sC[nloc * 72 + 16 * mi + 4 * kb + r] = (_Float16)(acc[mi][ni][r] + bia);
      }
    }
    __syncthreads();
    int row = tid >> 1, part = tid & 1;
    int n = 256 * hh2 + row;
    int n2 = (n & 127) * 4 + (n >> 7);     // j*4 + q
#pragma unroll
    for (int g = 0; g < 2; ++g) {
      int bg = part * 2 + g;
      _Float16* po = pre0 + (((long)t * NBG + bg) * 512 + n2) * 16;
      *(v8h*)po       = *(const v8h*)&sC[row * 72 + bg * 16];
      *(v8h*)(po + 8) = *(const v8h*)&sC[row * 72 + bg * 16 + 8];
    }
  }
}

// ---------------- persistent pipelined LSTM ----------------
// 80 blocks (layer l, batch-group of 16). 8 waves; wave w owns j-strip
// [16w,16w+16) x 4 gates; weights register-resident; no lane repack.
// y/pre operands: global->reg, 2-deep prefetch, vmcnt(4) counted waits;
// NO stores mid-chunk (bulk LDS->ring copy at chunk end only).
// LDS = 8 rotating h slots x 4KB = 32KB.
__global__ __launch_bounds__(512, 1) void lstm_pipe(
    const _Float16* __restrict__ pre0, const _Float16* __restrict__ Wc,
    const float* __restrict__ biasc, _Float16* __restrict__ yring,
    unsigned* __restrict__ flags, float* __restrict__ out)
{
  __shared__ __align__(16) unsigned char lds[32768];
  const int l = blockIdx.x >> 2, bg = blockIdx.x & 3;
  const int tid = threadIdx.x, w = tid >> 6, lane = tid & 63;
  const int l15 = lane & 15, kb = lane >> 4;
  const int jloc = 16 * w + l15;

  // weight fragments resident for the whole kernel (128 VGPRs)
  v8h bw[4][8];
  const _Float16* wbase = Wc + (long)l * G4 * 256;
#pragma unroll
  for (int q = 0; q < 4; ++q)
#pragma unroll
    for (int ks = 0; ks < 8; ++ks)
      bw[q][ks] = *(const v8h*)(wbase + (long)(128 * q + jloc) * 256 + ks * 32 + kb * 8);

  float bias_q[4];
#pragma unroll
  for (int q = 0; q < 4; ++q)
    bias_q[q] = (l == 0) ? 0.0f : biasc[l * G4 + 128 * q + jloc];

  // zero h slot 7 (the only one read before first write)
  *(v2u*)(lds + 7 * 4096 + tid * 8) = (v2u){0u, 0u};

  const int myf = l * NBG + bg;
  const unsigned* fin  = flags + ((l > 0) ? (myf - NBG) : myf);
  const unsigned* fout = flags + ((l < NL - 1) ? (myf + NBG) : myf);
  unsigned* fme = flags + myf;
  char* ywr = (char*)yring + (long)myf * FLOWB;
  const char* yrd = (char*)yring + (long)(myf - NBG) * FLOWB;
  const char* pbase = (const char*)pre0 + (long)bg * 16384 + jloc * 128 + kb * 8;

  // chunk-end bulk-copy mapping (waves 0-3)
  const int cks = tid >> 6, lane6 = tid & 63;
  const int csrc = swz(lane6 & 15, cks * 64 + (lane6 >> 4) * 16);
  const int cdst = cks * 1024 + lane6 * 16;

  v4f cst = (v4f){0.f, 0.f, 0.f, 0.f};
  v4u ya[4], yb[4];   // y fragment banks (l>0)
  v2u pa[4], pb[4];   // pre-gate banks (l==0)

  __syncthreads();

#define ISSUE_Y(D, yslot_, ts_) do { \
    const char* a_ = (yslot_) + (long)(ts_) * SLOT + lane * 16; \
    asm volatile("global_load_dwordx4 %0, %4, off sc0 sc1\n\t" \
                 "global_load_dwordx4 %1, %4, off offset:1024 sc0 sc1\n\t" \
                 "global_load_dwordx4 %2, %4, off offset:2048 sc0 sc1\n\t" \
                 "global_load_dwordx4 %3, %4, off offset:3072 sc0 sc1" \
                 : "=v"(D[0]), "=v"(D[1]), "=v"(D[2]), "=v"(D[3]) : "v"(a_)); \
  } while (0)

#define ISSUE_P(D, t_) do { \
    const char* a_ = pbase + (long)(t_) * (NBG * 16384); \
    asm volatile("global_load_dwordx2 %0, %4, off\n\t" \
                 "global_load_dwordx2 %1, %4, off offset:32\n\t" \
                 "global_load_dwordx2 %2, %4, off offset:64\n\t" \
                 "global_load_dwordx2 %3, %4, off offset:96" \
                 : "=v"(D[0]), "=v"(D[1]), "=v"(D[2]), "=v"(D[3]) : "v"(a_)); \
  } while (0)

// STEP ts_ uses bank YB/PB (== ts_&1) and re-issues ts_+2 into the same bank.
#define STEPX(ts_, YB, PB) do { \
    const int t = c * CK + (ts_); \
    if ((ts_) == CK - 1) asm volatile("s_waitcnt vmcnt(0)" ::: "memory"); \
    else asm volatile("s_waitcnt vmcnt(4)" ::: "memory"); \
    __builtin_amdgcn_sched_barrier(0); \
    v4f acc[4]; \
    _Pragma("unroll") \
    for (int q = 0; q < 4; ++q) \
      acc[q] = (v4f){bias_q[q], bias_q[q], bias_q[q], bias_q[q]}; \
    const unsigned char* hb = lds + (((ts_) + 7) & 7) * 4096; \
    v8h hfr[4]; \
    _Pragma("unroll") \
    for (int ks = 0; ks < 4; ++ks) \
      hfr[ks] = *(const v8h*)(hb + swz(l15, ks * 64 + kb * 16)); \
    if (l > 0) { \
      _Pragma("unroll") \
      for (int ks = 0; ks < 4; ++ks) { \
        union { v4u u; v8h h; } cv_; cv_.u = YB[ks]; \
        _Pragma("unroll") \
        for (int q = 0; q < 4; ++q) \
          acc[q] = __builtin_amdgcn_mfma_f32_16x16x32_f16(cv_.h, bw[q][ks], acc[q], 0, 0, 0); \
      } \
    } else { \
      _Pragma("unroll") \
      for (int q = 0; q < 4; ++q) { \
        union { v2u u; _Float16 h[4]; } pv_; pv_.u = PB[q]; \
        _Pragma("unroll") \
        for (int r = 0; r < 4; ++r) acc[q][r] += (float)pv_.h[r]; \
      } \
    } \
    if ((ts_) + 2 < CK) { \
      if (l > 0) ISSUE_Y(YB, yslot, (ts_) + 2); \
      else ISSUE_P(PB, t + 2); \
    } \
    _Pragma("unroll") \
    for (int ks = 0; ks < 4; ++ks) { \
      _Pragma("unroll") \
      for (int q = 0; q < 4; ++q) \
        acc[q] = __builtin_amdgcn_mfma_f32_16x16x32_f16(hfr[ks], bw[q][ks + 4], acc[q], 0, 0, 0); \
    } \
    float hf[4]; \
    _Pragma("unroll") \
    for (int r = 0; r < 4; ++r) { \
      float i_ = fast_sig(acc[0][r]); \
      float f_ = fast_sig(acc[1][r]); \
      float g_ = fast_tanh(acc[2][r]); \
      float o_ = fast_sig(acc[3][r]); \
      float cn = f_ * cst[r] + i_ * g_; \
      cst[r] = cn; \
      hf[r] = o_ * fast_tanh(cn); \
    } \
    unsigned char* hn = lds + ((ts_) & 7) * 4096; \
    _Pragma("unroll") \
    for (int r = 0; r < 4; ++r) \
      *(_Float16*)(hn + swz(4 * kb + r, jloc * 2)) = (_Float16)hf[r]; \
    if (l == NL - 1 && t == TT - 1) { \
      _Pragma("unroll") \
      for (int r = 0; r < 4; ++r) \
        out[(bg * 16 + 4 * kb + r) * H4 + jloc] = hf[r]; \
    } \
    asm volatile("s_waitcnt lgkmcnt(0)" ::: "memory"); \
    __builtin_amdgcn_s_barrier(); \
    __builtin_amdgcn_sched_barrier(0); \
  } while (0)

  for (int c = 0; c < NCH; ++c) {
    const char* yslot = yrd + (long)(c & (RC - 1)) * CHUNK;
    char* ywslot = ywr + (long)(c & (RC - 1)) * CHUNK;

    if (l > 0) {
      unsigned f;
      for (;;) {
        asm volatile("global_load_dword %0, %1, off sc0 sc1\n\ts_waitcnt vmcnt(0)"
                     : "=v"(f) : "v"(fin));
        if (f > (unsigned)c) break;
        __builtin_amdgcn_s_sleep(2);
      }
      ISSUE_Y(ya, yslot, 0);
      ISSUE_Y(yb, yslot, 1);
    } else {
      ISSUE_P(pa, c * CK);
      ISSUE_P(pb, c * CK + 1);
    }

    STEPX(0, ya, pa);
    STEPX(1, yb, pb);
    STEPX(2, ya, pa);
    STEPX(3, yb, pb);
    STEPX(4, ya, pa);
    STEPX(5, yb, pb);
    STEPX(6, ya, pa);
    STEPX(7, yb, pb);

    // chunk end: backpressure, bulk LDS->ring copy, drain, publish
    if (l < NL - 1) {
      if (c >= RC) {
        unsigned f;
        for (;;) {
          asm volatile("global_load_dword %0, %1, off sc0 sc1\n\ts_waitcnt vmcnt(0)"
                       : "=v"(f) : "v"(fout));
          if (f >= (unsigned)(c - RC + 1)) break;
          __builtin_amdgcn_s_sleep(2);
        }
      }
      if (tid < 256) {
#pragma unroll
        for (int ts = 0; ts < CK; ++ts) {
          v4u hv = *(const v4u*)(lds + ts * 4096 + csrc);
          asm volatile("global_store_dwordx4 %0, %1, off sc0 sc1"
                       :: "v"(ywslot + ts * 4096 + cdst), "v"(hv) : "memory");
        }
      }
    }
    asm volatile("s_waitcnt vmcnt(0)" ::: "memory");
    __builtin_amdgcn_s_barrier();
    __builtin_amdgcn_sched_barrier(0);
    if (tid == 0) {
      unsigned v = (unsigned)(c + 1);
      asm volatile("global_store_dword %0, %1, off sc0 sc1" :: "v"(fme), "v"(v) : "memory");
    }
  }
#undef STEPX
#undef ISSUE_Y
#undef ISSUE_P
}

extern "C" void kernel_launch(void* const* d_in, const int* in_sizes, int n_in,
                              void* d_out, int out_size, void* d_ws, size_t ws_size,
                              hipStream_t stream)
{
  const float* x    = (const float*)d_in[0];
  const float* Wih0 = (const float*)d_in[1];
  const float* Whh0 = (const float*)d_in[2];
  const float* bih0 = (const float*)d_in[3];
  const float* bhh0 = (const float*)d_in[4];
  const float* Wih  = (const float*)d_in[5];
  const float* Whh  = (const float*)d_in[6];
  const float* bih  = (const float*)d_in[7];
  const float* bhh  = (const float*)d_in[8];
  float* out = (float*)d_out;
  char* ws = (char*)d_ws;

  _Float16* pre0  = (_Float16*)(ws);              // 33,554,432 B
  _Float16* W0h   = (_Float16*)(ws + 33554432);   //    786,432 B
  _Float16* Wc    = (_Float16*)(ws + 34340864);   //  5,242,880 B
  float*    bc    = (float*)   (ws + 39583744);   //     40,960 B
  _Float16* yring = (_Float16*)(ws + 39624704);   // 10,485,760 B (80 flows x 128KB)
  unsigned* flags = (unsigned*)(ws + 50110464);   //      1,024 B

  prep_kernel<<<11817, 256, 0, stream>>>(Wih0, Whh0, bih, bhh, Wih, Whh, W0h, Wc, bc, flags);
  pre0_gemm<<<TT, 512, 0, stream>>>(x, W0h, bih0, bhh0, pre0);
  lstm_pipe<<<NL * NBG, 512, 0, stream>>>(pre0, Wc, bc, yring, flags, out);
}

// Round 12
// 1014.073 us; speedup vs baseline: 1.5156x; 1.0936x over previous
//
#include <hip/hip_runtime.h>

#define H4 128     // hidden
#define EE 768     // embedding
#define NL 20      // layers
#define TT 512     // seq len
#define G4 512     // 4*H
#define NBG 8      // batch groups of 8
#define CK 8       // timesteps per chunk
#define NCH (TT/CK)
#define RC 2       // ring slots (chunks) per flow
#define SLOT 4096  // ring bytes per step (A-fragment image; rows 8-15 unused)
#define CHUNK (CK*SLOT)
#define FLOWB (RC*CHUNK)

typedef _Float16 v8h __attribute__((ext_vector_type(8)));
typedef _Float16 v4h __attribute__((ext_vector_type(4)));
typedef float v4f __attribute__((ext_vector_type(4)));
typedef unsigned int v4u __attribute__((ext_vector_type(4)));
typedef unsigned int v2u __attribute__((ext_vector_type(2)));

#if defined(__has_builtin)
#if __has_builtin(__builtin_amdgcn_exp2f) && __has_builtin(__builtin_amdgcn_rcpf)
#define EXP2F __builtin_amdgcn_exp2f
#define RCPF  __builtin_amdgcn_rcpf
#endif
#endif
#ifndef EXP2F
#define EXP2F exp2f
#define RCPF(x) (1.0f/(x))
#endif

__device__ __forceinline__ float fast_sig(float x) {
  float e = EXP2F(-1.44269504f * x);
  return RCPF(1.0f + e);
}
__device__ __forceinline__ float fast_tanh(float x) {
  float e = EXP2F(2.88539008f * x);   // e^(2x)
  return 1.0f - 2.0f * RCPF(1.0f + e);
}

// XOR swizzle within a [16 rows][256B] tile (PMC-proven conflict-free in r7/r8).
__device__ __forceinline__ int swz(int row, int byteInRow) {
  return (row * 256 + byteInRow) ^ ((row & 15) << 4);
}

// ---------------- prep: fp16 weights, combined bias, flags, zero yring ----------------
__global__ __launch_bounds__(256) void prep_kernel(
    const float* __restrict__ Wih0, const float* __restrict__ Whh0,
    const float* __restrict__ bih,  const float* __restrict__ bhh,
    const float* __restrict__ Wih,  const float* __restrict__ Whh,
    _Float16* __restrict__ W0h, _Float16* __restrict__ Wc,
    float* __restrict__ biasc, unsigned* __restrict__ flags,
    _Float16* __restrict__ yring)
{
  long idx = (long)blockIdx.x * 256 + threadIdx.x;
  const long NWC = (long)NL * G4 * 256;   // 2,621,440
  const long NW0 = (long)G4 * EE;         // 393,216
  const long NBI = (long)NL * G4;         // 10,240
  const long NYR = (long)NL * NBG * FLOWB / 16;  // 655,360 v4u
  if (idx < NWC) {
    int l = (int)(idx >> 17);
    int rem = (int)(idx & 131071);
    int n = rem >> 8, kk = rem & 255;
    float v;
    if (l == 0) v = (kk < 128) ? 0.0f : Whh0[n * H4 + kk - 128];
    else v = (kk < 128) ? Wih[((long)(l-1) * G4 + n) * H4 + kk]
                        : Whh[((long)(l-1) * G4 + n) * H4 + kk - 128];
    Wc[idx] = (_Float16)v;
  } else if ((idx -= NWC) < NW0) {
    W0h[idx] = (_Float16)Wih0[idx];
  } else if ((idx -= NW0) < NBI) {
    int l = (int)(idx >> 9), n = (int)(idx & 511);
    biasc[idx] = (l == 0) ? 0.0f : (bih[(l-1) * G4 + n] + bhh[(l-1) * G4 + n]);
  } else if ((idx -= NBI) < 256) {
    flags[idx] = 0u;
  } else if ((idx -= 256) < NYR) {
    ((v4u*)yring)[idx] = (v4u){0u, 0u, 0u, 0u};
  }
}

// ---------------- layer-0 input projection GEMM ----------------
// pre0 layout: [t][bg(8)][n2 = j*4+q (512)][b(8)] fp16 -> 8KB per (t,bg).
__global__ __launch_bounds__(512) void pre0_gemm(
    const float* __restrict__ x, const _Float16* __restrict__ W0h,
    const float* __restrict__ bih0, const float* __restrict__ bhh0,
    _Float16* __restrict__ pre0)
{
  __shared__ __align__(16) unsigned char smem[46080];
  _Float16* sA = (_Float16*)smem;             // [64][40]
  _Float16* sB = (_Float16*)(smem + 5120);    // [512][40]
  _Float16* sC = (_Float16*)smem;             // alias: [256][72] bounce
  int t = blockIdx.x;
  int tid = threadIdx.x;
  int w = tid >> 6, lane = tid & 63;
  int l15 = lane & 15, kb = lane >> 4;

  v4f acc[4][4];
#pragma unroll
  for (int mi = 0; mi < 4; ++mi)
#pragma unroll
    for (int ni = 0; ni < 4; ++ni) acc[mi][ni] = (v4f){0.f, 0.f, 0.f, 0.f};

  int bA = tid >> 3, kqA = tid & 7;
  const float* xp = x + ((long)bA * TT + t) * EE + kqA * 4;
  const _Float16* wp = W0h + (long)tid * EE;

  for (int k0 = 0; k0 < EE; k0 += 32) {
    float4 xv = *(const float4*)(xp + k0);
    v4h xh = { (_Float16)xv.x, (_Float16)xv.y, (_Float16)xv.z, (_Float16)xv.w };
    *(v4h*)&sA[bA * 40 + kqA * 4] = xh;
#pragma unroll
    for (int c = 0; c < 4; ++c)
      *(v8h*)&sB[tid * 40 + c * 8] = *(const v8h*)(wp + k0 + c * 8);
    __syncthreads();
#pragma unroll
    for (int mi = 0; mi < 4; ++mi) {
      v8h a = *(const v8h*)&sA[(16 * mi + l15) * 40 + kb * 8];
#pragma unroll
      for (int ni = 0; ni < 4; ++ni) {
        v8h b = *(const v8h*)&sB[(64 * w + 16 * ni + l15) * 40 + kb * 8];
        acc[mi][ni] = __builtin_amdgcn_mfma_f32_16x16x32_f16(a, b, acc[mi][ni], 0, 0, 0);
      }
    }
    __syncthreads();
  }

#pragma unroll
  for (int hh2 = 0; hh2 < 2; ++hh2) {
    __syncthreads();
    if ((w >> 2) == hh2) {
      int wl = w & 3;
#pragma unroll
      for (int ni = 0; ni < 4; ++ni) {
        int nloc = 64 * wl + 16 * ni + l15;
        int n = 256 * hh2 + nloc;
        float bia = bih0[n] + bhh0[n];
#pragma unroll
        for (int mi = 0; mi < 4; ++mi)
#pragma unroll
          for (int r = 0; r < 4; ++r)
            sC[nloc * 72 + 16 * mi + 4 * kb + r] = (_Float16)(acc[mi][ni][r] + bia);
      }
    }
    __syncthreads();
    int row = tid >> 1, part = tid & 1;
    int n = 256 * hh2 + row;
    int n2 = (n & 127) * 4 + (n >> 7);     // j*4 + q
#pragma unroll
    for (int g = 0; g < 4; ++g) {
      int bgi = part * 4 + g;              // batch group of 8
      _Float16* po = pre0 + (((long)t * NBG + bgi) * 512 + n2) * 8;
      *(v8h*)po = *(const v8h*)&sC[row * 72 + bgi * 8];
    }
  }
}

// ---------------- persistent pipelined LSTM ----------------
// 160 blocks (layer l, batch-group of 8). 8 waves; wave w owns j-strip
// [16w,16w+16) x 4 gates; weights register-resident. r8-PROVEN step structure
// (vmcnt at step top, ISSUE mid-step, operands consumed same step) + r6-PROVEN
// shfl_xor gate repack (lane owns rows 2rp,2rp+1; 20 trans/lane).
// Rows 8-15 of MFMA D are garbage (OOB pre reads / unwritten ring rows) and
// provably discarded by the repack. LDS = 8 rotating h slots x 4KB.
__global__ __launch_bounds__(512, 1) void lstm_pipe(
    const _Float16* __restrict__ pre0, const _Float16* __restrict__ Wc,
    const float* __restrict__ biasc, _Float16* __restrict__ yring,
    unsigned* __restrict__ flags, float* __restrict__ out)
{
  __shared__ __align__(16) unsigned char lds[32768];
  const int l = blockIdx.x >> 3, bg = blockIdx.x & 7;
  const int tid = threadIdx.x, w = tid >> 6, lane = tid & 63;
  const int l15 = lane & 15, kb = lane >> 4;
  const int jloc = 16 * w + l15;
  const bool lo = (kb < 2);
  const int rp = (kb & 1) * 2 + (kb >> 1);   // lane owns h rows 2rp, 2rp+1

  // weight fragments resident for the whole kernel
  v8h bw[4][8];
  const _Float16* wbase = Wc + (long)l * G4 * 256;
#pragma unroll
  for (int q = 0; q < 4; ++q)
#pragma unroll
    for (int ks = 0; ks < 8; ++ks)
      bw[q][ks] = *(const v8h*)(wbase + (long)(128 * q + jloc) * 256 + ks * 32 + kb * 8);

  float bias_q[4];
#pragma unroll
  for (int q = 0; q < 4; ++q)
    bias_q[q] = (l == 0) ? 0.0f : biasc[l * G4 + 128 * q + jloc];

  // zero all 8 h slots (slot 7 must be zero for the first step's h-read)
  for (int i = tid; i < 2048; i += 512)
    *(v4u*)(lds + i * 16) = (v4u){0u, 0u, 0u, 0u};

  const int myf = l * NBG + bg;
  const unsigned* fin  = flags + ((l > 0) ? (myf - NBG) : myf);
  const unsigned* fout = flags + ((l < NL - 1) ? (myf + NBG) : myf);
  unsigned* fme = flags + myf;
  char* ywr = (char*)yring + (long)myf * FLOWB;
  const char* yrd = (char*)yring + (long)(myf - NBG) * FLOWB;
  const char* pbase = (const char*)pre0 + (long)bg * 8192 + jloc * 64 + kb * 8;

  float c0 = 0.f, c1 = 0.f;
  v4u ya[4], yb[4];   // y fragment banks (l>0)
  v2u pa[4], pb[4];   // pre-gate banks (l==0)

  __syncthreads();

#define ISSUE_Y(D, ts_) do { \
    const char* a_ = yslot + (long)(ts_) * SLOT + lane * 16; \
    asm volatile("global_load_dwordx4 %0, %4, off sc0 sc1\n\t" \
                 "global_load_dwordx4 %1, %4, off offset:1024 sc0 sc1\n\t" \
                 "global_load_dwordx4 %2, %4, off offset:2048 sc0 sc1\n\t" \
                 "global_load_dwordx4 %3, %4, off offset:3072 sc0 sc1" \
                 : "=v"(D[0]), "=v"(D[1]), "=v"(D[2]), "=v"(D[3]) : "v"(a_)); \
  } while (0)

#define ISSUE_P(D, t_) do { \
    const char* a_ = pbase + (long)(t_) * (NBG * 8192); \
    asm volatile("global_load_dwordx2 %0, %4, off\n\t" \
                 "global_load_dwordx2 %1, %4, off offset:16\n\t" \
                 "global_load_dwordx2 %2, %4, off offset:32\n\t" \
                 "global_load_dwordx2 %3, %4, off offset:48" \
                 : "=v"(D[0]), "=v"(D[1]), "=v"(D[2]), "=v"(D[3]) : "v"(a_)); \
  } while (0)

// r8-proven step shape: wait at top, consume bank this step, re-issue ts+2.
#define STEPX(ts_, YB, PB) do { \
    const int t = c * CK + (ts_); \
    if ((ts_) == CK - 1) asm volatile("s_waitcnt vmcnt(0)" ::: "memory"); \
    else asm volatile("s_waitcnt vmcnt(4)" ::: "memory"); \
    __builtin_amdgcn_sched_barrier(0); \
    v4f acc[4]; \
    _Pragma("unroll") \
    for (int q = 0; q < 4; ++q) \
      acc[q] = (v4f){bias_q[q], bias_q[q], bias_q[q], bias_q[q]}; \
    const unsigned char* hb = lds + (((ts_) + 7) & 7) * 4096; \
    v8h hfr[4]; \
    _Pragma("unroll") \
    for (int ks = 0; ks < 4; ++ks) \
      hfr[ks] = *(const v8h*)(hb + swz(l15, ks * 64 + kb * 16)); \
    if (l > 0) { \
      _Pragma("unroll") \
      for (int ks = 0; ks < 4; ++ks) { \
        union { v4u u; v8h h; } cv_; cv_.u = YB[ks]; \
        _Pragma("unroll") \
        for (int q = 0; q < 4; ++q) \
          acc[q] = __builtin_amdgcn_mfma_f32_16x16x32_f16(cv_.h, bw[q][ks], acc[q], 0, 0, 0); \
      } \
    } else { \
      _Pragma("unroll") \
      for (int q = 0; q < 4; ++q) { \
        union { v2u u; _Float16 h[4]; } pv_; pv_.u = PB[q]; \
        _Pragma("unroll") \
        for (int r = 0; r < 4; ++r) acc[q][r] += (float)pv_.h[r]; \
      } \
    } \
    if ((ts_) + 2 < CK) { \
      if (l > 0) ISSUE_Y(YB, (ts_) + 2); \
      else ISSUE_P(PB, t + 2); \
    } \
    _Pragma("unroll") \
    for (int ks = 0; ks < 4; ++ks) { \
      _Pragma("unroll") \
      for (int q = 0; q < 4; ++q) \
        acc[q] = __builtin_amdgcn_mfma_f32_16x16x32_f16(hfr[ks], bw[q][ks + 4], acc[q], 0, 0, 0); \
    } \
    float w0[4], w1[4]; \
    _Pragma("unroll") \
    for (int q = 0; q < 4; ++q) { \
      v4f s = acc[q]; \
      float t2 = __shfl_xor(s[2], 32); \
      float t3 = __shfl_xor(s[3], 32); \
      w0[q] = lo ? s[0] : t2; \
      w1[q] = lo ? s[1] : t3; \
    } \
    float i0 = fast_sig(w0[0]), f0 = fast_sig(w0[1]); \
    float g0 = fast_tanh(w0[2]), o0 = fast_sig(w0[3]); \
    c0 = f0 * c0 + i0 * g0; \
    float h0 = o0 * fast_tanh(c0); \
    float i1 = fast_sig(w1[0]), f1 = fast_sig(w1[1]); \
    float g1 = fast_tanh(w1[2]), o1 = fast_sig(w1[3]); \
    c1 = f1 * c1 + i1 * g1; \
    float h1 = o1 * fast_tanh(c1); \
    unsigned char* hn = lds + ((ts_) & 7) * 4096; \
    *(_Float16*)(hn + swz(2 * rp,     jloc * 2)) = (_Float16)h0; \
    *(_Float16*)(hn + swz(2 * rp + 1, jloc * 2)) = (_Float16)h1; \
    if (l == NL - 1 && t == TT - 1) { \
      out[(bg * 8 + 2 * rp) * H4 + jloc]     = h0; \
      out[(bg * 8 + 2 * rp + 1) * H4 + jloc] = h1; \
    } \
    asm volatile("s_waitcnt lgkmcnt(0)" ::: "memory"); \
    __builtin_amdgcn_s_barrier(); \
    __builtin_amdgcn_sched_barrier(0); \
  } while (0)

  for (int c = 0; c < NCH; ++c) {
    const char* yslot = yrd + (long)(c & (RC - 1)) * CHUNK;
    char* ywslot = ywr + (long)(c & (RC - 1)) * CHUNK;

    if (l > 0) {
      unsigned f;
      for (;;) {
        asm volatile("global_load_dword %0, %1, off sc0 sc1\n\ts_waitcnt vmcnt(0)"
                     : "=v"(f) : "v"(fin));
        if (f > (unsigned)c) break;
        __builtin_amdgcn_s_sleep(2);
      }
      ISSUE_Y(ya, 0);
      ISSUE_Y(yb, 1);
    } else {
      ISSUE_P(pa, c * CK);
      ISSUE_P(pb, c * CK + 1);
    }

    STEPX(0, ya, pa);
    STEPX(1, yb, pb);
    STEPX(2, ya, pa);
    STEPX(3, yb, pb);
    STEPX(4, ya, pa);
    STEPX(5, yb, pb);
    STEPX(6, ya, pa);
    STEPX(7, yb, pb);

    // chunk end: backpressure, bulk LDS->ring copy (rows 0-7 only), drain, publish
    if (l < NL - 1) {
      if (c >= RC) {
        unsigned f;
        for (;;) {
          asm volatile("global_load_dword %0, %1, off sc0 sc1\n\ts_waitcnt vmcnt(0)"
                       : "=v"(f) : "v"(fout));
          if (f >= (unsigned)(c - RC + 1)) break;
          __builtin_amdgcn_s_sleep(2);
        }
      }
#pragma unroll
      for (int pass = 0; pass < 2; ++pass) {
        const int u = tid + pass * 512;
        const int ts2 = u >> 7, ww = u & 127, bb = ww & 7, jb = ww >> 3;
        v4u hv = *(const v4u*)(lds + ts2 * 4096 + ((bb * 256 + jb * 16) ^ (bb << 4)));
        char* dst2 = ywslot + ts2 * 4096 + (jb >> 2) * 1024 + (bb + 16 * (jb & 3)) * 16;
        asm volatile("global_store_dwordx4 %0, %1, off sc0 sc1"
                     :: "v"(dst2), "v"(hv) : "memory");
      }
    }
    asm volatile("s_waitcnt vmcnt(0)" ::: "memory");
    __builtin_amdgcn_s_barrier();
    __builtin_amdgcn_sched_barrier(0);
    if (tid == 0) {
      unsigned v = (unsigned)(c + 1);
      asm volatile("global_store_dword %0, %1, off sc0 sc1" :: "v"(fme), "v"(v) : "memory");
    }
  }
#undef STEPX
#undef ISSUE_Y
#undef ISSUE_P
}

extern "C" void kernel_launch(void* const* d_in, const int* in_sizes, int n_in,
                              void* d_out, int out_size, void* d_ws, size_t ws_size,
                              hipStream_t stream)
{
  const float* x    = (const float*)d_in[0];
  const float* Wih0 = (const float*)d_in[1];
  const float* Whh0 = (const float*)d_in[2];
  const float* bih0 = (const float*)d_in[3];
  const float* bhh0 = (const float*)d_in[4];
  const float* Wih  = (const float*)d_in[5];
  const float* Whh  = (const float*)d_in[6];
  const float* bih  = (const float*)d_in[7];
  const float* bhh  = (const float*)d_in[8];
  float* out = (float*)d_out;
  char* ws = (char*)d_ws;

  _Float16* pre0  = (_Float16*)(ws);              // 33,554,432 B
  _Float16* W0h   = (_Float16*)(ws + 33554432);   //    786,432 B
  _Float16* Wc    = (_Float16*)(ws + 34340864);   //  5,242,880 B
  float*    bc    = (float*)   (ws + 39583744);   //     40,960 B
  _Float16* yring = (_Float16*)(ws + 39624704);   // 10,485,760 B (160 flows x 64KB)
  unsigned* flags = (unsigned*)(ws + 50110464);   //      1,024 B

  prep_kernel<<<14377, 256, 0, stream>>>(Wih0, Whh0, bih, bhh, Wih, Whh, W0h, Wc, bc, flags, yring);
  pre0_gemm<<<TT, 512, 0, stream>>>(x, W0h, bih0, bhh0, pre0);
  lstm_pipe<<<NL * NBG, 512, 0, stream>>>(pre0, Wc, bc, yring, flags, out);
}